// Round 8
// baseline (87.498 us; speedup 1.0000x reference)
//
#include <hip/hip_runtime.h>

#define PI_D 3.14159265358979323846264338327950288

// Twiddle / EXTRA tables in module globals, rewritten every launch.
__device__ float2 g_tw[3 * 256];
__device__ float2 g_ex[257];

__device__ __forceinline__ float quant_floor(float v, float s, float is, float lo, float hi) {
    return fminf(fmaxf(floorf(v * s) * is, lo), hi);
}

// Build TWIDDLE (3 rows x 256) / EXTRA (257) exactly as the reference:
// round-half-even to (6,4)/(4,2) fixed point + the _w_N special-case ladder.
__global__ void setup_tables_kernel() {
    int idx = blockIdx.x * blockDim.x + threadIdx.x;
    if (idx < 3 * 256) {
        int t = idx >> 8;            // row (stage/2 - 1)
        int n = idx & 255;
        int bl = 6 - 2 * t;          // log2(n3)
        int j = (n >> bl) & 3;       // quarter: [1, W^2i, W^i, W^3i]
        int i = n & ((1 << bl) - 1);
        int fj = (j == 0) ? 0 : (j == 1) ? 2 : (j == 2) ? 1 : 3;
        double sN = (double)(1 << (8 - 2 * t));   // 256, 64, 16
        double ang = -2.0 * PI_D * (double)(fj * i) / sN;
        float c = (float)cos(ang);
        float s = (float)sin(ang);
        float cf = fminf(fmaxf(rintf(c * 16.0f) * 0.0625f, -2.0f), 1.9375f);
        float sf = fminf(fmaxf(rintf(s * 16.0f) * 0.0625f, -2.0f), 1.9375f);
        float2 w;
        if (cf == 1.0f)       w = make_float2( 1.0f,  0.0f);
        else if (cf == -1.0f) w = make_float2(-1.0f,  0.0f);
        else if (sf == 1.0f)  w = make_float2( 0.0f,  1.0f);
        else if (sf == -1.0f) w = make_float2( 0.0f, -1.0f);
        else                  w = make_float2(cf, sf);
        g_tw[idx] = w;
    }
    if (idx < 257) {
        double ang = -PI_D * (double)idx / 256.0;
        float c = (float)cos(ang);
        float s = (float)sin(ang);
        float er = fminf(fmaxf(rintf(c * 4.0f) * 0.25f, -2.0f), 1.75f);
        float ei = fminf(fmaxf(rintf(s * 4.0f) * 0.25f, -2.0f), 1.75f);
        g_ex[idx] = make_float2(er, ei);
    }
}

// One wave per row; lane l holds complex elements 4l..4l+3 in registers.
// Stages 1..6 via shfl_xor, 7..8 intra-lane; bitrev via LDS; real-FFT untangle.
// OUTPUT: REAL PART ONLY, out[row*257 + k] — the harness compares
// ref.astype(float32) (= real part) over (8,2048,257); out_size = 4,210,688.
__global__ __launch_bounds__(256) void r22sdf_fft_kernel(
    const float* __restrict__ x, float* __restrict__ out,
    long long n_x, long long n_out_f, int rows)
{
    __shared__ float2 lds[4][256];
    const int tid  = threadIdx.x;
    const int lane = tid & 63;
    const int wv   = tid >> 6;
    const int row  = blockIdx.x * 4 + wv;
    if (row >= rows) return;

    const long long base = (long long)row * 512 + 8 * lane;
    float4 a0 = make_float4(0.f, 0.f, 0.f, 0.f);
    float4 a1 = a0;
    if (base + 7 < n_x) {
        a0 = *reinterpret_cast<const float4*>(x + base);
        a1 = *reinterpret_cast<const float4*>(x + base + 4);
    }

    // z[n] = (x[2n] + i x[2n+1]) * PRE_GAIN, n = 4*lane + k
    float zr[4], zi[4];
    zr[0] = a0.x * 16.0f; zi[0] = a0.y * 16.0f;
    zr[1] = a0.z * 16.0f; zi[1] = a0.w * 16.0f;
    zr[2] = a1.x * 16.0f; zi[2] = a1.y * 16.0f;
    zr[3] = a1.z * 16.0f; zi[3] = a1.w * 16.0f;

    // per-stage quant params (stages 1..7)
    const float QS[7]  = {64.f, 64.f, 32.f, 32.f, 8.f, 8.f, 4.f};
    const float QIS[7] = {1.f/64.f, 1.f/64.f, 1.f/32.f, 1.f/32.f, 0.125f, 0.125f, 0.25f};
    const float QLO[7] = {-2.f, -2.f, -4.f, -4.f, -16.f, -16.f, -32.f};
    const float QHI[7] = {2.f - 1.f/64.f, 2.f - 1.f/64.f, 4.f - 1.f/32.f, 4.f - 1.f/32.f,
                          16.f - 0.125f, 16.f - 0.125f, 31.75f};

#pragma unroll
    for (int s = 1; s <= 6; ++s) {
        const int mask = 64 >> s;
        const bool upper = (lane & mask) != 0;
#pragma unroll
        for (int k = 0; k < 4; ++k) {
            const float tr = __shfl_xor(zr[k], mask, 64);
            const float ti = __shfl_xor(zi[k], mask, 64);
            zr[k] = upper ? (tr - zr[k]) : (zr[k] + tr);
            zi[k] = upper ? (ti - zi[k]) : (zi[k] + ti);
        }
        if (s & 1) {
#pragma unroll
            for (int k = 0; k < 4; ++k) {
                const int n = 4 * lane + k;
                const bool m = ((n >> (7 - s)) & 3) == 3;
                const float t = zr[k];
                zr[k] = m ? zi[k] : zr[k];
                zi[k] = m ? -t    : zi[k];
            }
        } else {
            const float2* wrow = g_tw + ((s >> 1) - 1) * 256 + 4 * lane;
#pragma unroll
            for (int k = 0; k < 4; ++k) {
                const float2 w = wrow[k];
                const float nr = zr[k] * w.x - zi[k] * w.y;
                const float ni = zr[k] * w.y + zi[k] * w.x;
                zr[k] = nr; zi[k] = ni;
            }
        }
#pragma unroll
        for (int k = 0; k < 4; ++k) {
            zr[k] = quant_floor(zr[k], QS[s-1], QIS[s-1], QLO[s-1], QHI[s-1]);
            zi[k] = quant_floor(zi[k], QS[s-1], QIS[s-1], QLO[s-1], QHI[s-1]);
        }
    }

    // stage 7: pairs (0,2),(1,3); -i on slot3; quant (8,2)
    {
        float t0r = zr[0] + zr[2], t0i = zi[0] + zi[2];
        float t2r = zr[0] - zr[2], t2i = zi[0] - zi[2];
        float t1r = zr[1] + zr[3], t1i = zi[1] + zi[3];
        float t3r = zr[1] - zr[3], t3i = zi[1] - zi[3];
        zr[0] = t0r; zi[0] = t0i;
        zr[1] = t1r; zi[1] = t1i;
        zr[2] = t2r; zi[2] = t2i;
        zr[3] = t3i; zi[3] = -t3r;
#pragma unroll
        for (int k = 0; k < 4; ++k) {
            zr[k] = quant_floor(zr[k], 4.f, 0.25f, -32.f, 31.75f);
            zi[k] = quant_floor(zi[k], 4.f, 0.25f, -32.f, 31.75f);
        }
    }
    // stage 8: pairs (0,1),(2,3); no twiddle, no quant
    {
        float t0r = zr[0] + zr[1], t0i = zi[0] + zi[1];
        float t1r = zr[0] - zr[1], t1i = zi[0] - zi[1];
        float t2r = zr[2] + zr[3], t2i = zi[2] + zi[3];
        float t3r = zr[2] - zr[3], t3i = zi[2] - zi[3];
        zr[0] = t0r; zi[0] = t0i; zr[1] = t1r; zi[1] = t1i;
        zr[2] = t2r; zi[2] = t2i; zr[3] = t3r; zi[3] = t3i;
    }

    // bit-reversed store into LDS (rev8 is an involution)
#pragma unroll
    for (int k = 0; k < 4; ++k) {
        const int n = 4 * lane + k;
        const int p = (int)(__brev((unsigned)n) >> 24);
        lds[wv][p] = make_float2(zr[k], zi[k]);
    }
    __syncthreads();

    // real-FFT untangle: re(out[k]) = re(x_even + EXTRA[k]*x_odd), quant (8,2), /16
    const long long obase = (long long)row * 257;
    auto emit = [&](int k) {
        const int kk = k & 255;
        const int km = (256 - kk) & 255;
        const float2 y  = lds[wv][kk];
        const float2 ym = lds[wv][km];          // zr-term = conj(Y[(256-k)%256])
        const float xer  = 0.5f * (y.x + ym.x);
        const float xodr = 0.5f * (y.y + ym.y);
        const float xodi = 0.5f * (ym.x - y.x);
        const float2 E = g_ex[k];
        float re = xer + (E.x * xodr - E.y * xodi);
        re = quant_floor(re, 4.f, 0.25f, -32.f, 31.75f) * 0.0625f;
        const long long f1 = obase + k;
        if (f1 < n_out_f) out[f1] = re;
    };
#pragma unroll
    for (int j = 0; j < 4; ++j) emit(64 * j + lane);
    if (lane == 0) emit(256);
}

extern "C" void kernel_launch(void* const* d_in, const int* in_sizes, int n_in,
                              void* d_out, int out_size, void* d_ws, size_t ws_size,
                              hipStream_t stream) {
    (void)d_ws; (void)ws_size; (void)n_in;
    const float* x = (const float*)d_in[0];
    float* out = (float*)d_out;
    hipLaunchKernelGGL(setup_tables_kernel, dim3(2), dim3(512), 0, stream);
    const long long n_x = (long long)in_sizes[0];
    const int rows = (int)(n_x / 512);                  // 16384 expected
    const int blocks = (rows + 3) / 4;                  // 4 rows (waves) / block
    hipLaunchKernelGGL(r22sdf_fft_kernel, dim3(blocks), dim3(256), 0, stream,
                       x, out, n_x, (long long)out_size, rows);
}